// Round 2
// baseline (4167.109 us; speedup 1.0000x reference)
//
#include <hip/hip_runtime.h>
#include <hip/hip_bf16.h>

#define ITER_TIME 32
#define DECAY 0.9f
#define KS 4         // K split for the recurrent GEMM
#define NBLK 272     // persistent grid: 2 Mtiles x 34 Ntiles x KS = 272

typedef __attribute__((ext_vector_type(8))) short short8;
typedef __attribute__((ext_vector_type(4))) float f32x4;
typedef __attribute__((ext_vector_type(4))) short short4v;
typedef unsigned short ushort_t;
typedef unsigned int u32;

// global -> LDS direct DMA, 16B per lane. Dest is wave-uniform base + lane*16.
__device__ __forceinline__ void gload16(const ushort_t* g, ushort_t* l) {
    __builtin_amdgcn_global_load_lds(
        (const __attribute__((address_space(1))) u32*)g,
        (__attribute__((address_space(3))) u32*)l, 16, 0, 0);
}

// ---------------------------------------------------------------------------
// Convert f32 -> bf16 elementwise (for x). Also zeroes the grid-barrier
// counter (runs before the persistent kernel on the same stream each replay).
// ---------------------------------------------------------------------------
__global__ void conv_f32_bf16(const float* __restrict__ in,
                              __hip_bfloat16* __restrict__ out, int n,
                              int* __restrict__ bar) {
    if (blockIdx.x == 0 && threadIdx.x == 0) *bar = 0;
    int i = blockIdx.x * 256 + threadIdx.x;
    if (i < n) out[i] = __float2bfloat16(in[i]);
}

// ---------------------------------------------------------------------------
// Fused convert + transpose: f32 in [R][C] -> bf16 out [C][R]
// ---------------------------------------------------------------------------
__global__ void transpose_f32_bf16(const float* __restrict__ in,
                                   __hip_bfloat16* __restrict__ out, int R,
                                   int C) {
    __shared__ float tile[32][33];
    int tx = threadIdx.x, ty = threadIdx.y;
    size_t x = blockIdx.x * 32 + tx;  // col in `in`
    size_t y = blockIdx.y * 32 + ty;  // row in `in`
    tile[ty][tx] = in[y * C + x];
    __syncthreads();
    size_t ox = blockIdx.y * 32 + tx;  // col in `out` (= row in `in`)
    size_t oy = blockIdx.x * 32 + ty;  // row in `out` (= col in `in`)
    out[oy * R + ox] = __float2bfloat16(tile[tx][ty]);
}

// ---------------------------------------------------------------------------
// One-time GEMM for i_ = x @ W_i (bf16 in, f32 out). Same structure as the
// persistent GEMM tile: global_load_lds staging, XOR swizzle, 2-phase dbuf.
// grid (2, Nmain/128, 1), block 256.
// ---------------------------------------------------------------------------
__global__ __launch_bounds__(256)
void gemm_wi(const ushort_t* __restrict__ A,   // [256][K] bf16
             const ushort_t* __restrict__ BT,  // [Nmain][K] bf16
             float* __restrict__ C,            // [256][Nmain] f32
             int K, int Nmain) {
    __shared__ __attribute__((aligned(16))) ushort_t As[2][128 * 64];
    __shared__ __attribute__((aligned(16))) ushort_t Bs[2][128 * 64];

    int m0 = blockIdx.x * 128;
    int by = blockIdx.y;
    const ushort_t* Bsrc = BT + (size_t)(by * 128) * K;

    int t = threadIdx.x;
    int wave = t >> 6, lane = t & 63;
    int quad = lane >> 4, l16 = lane & 15;
    int wm = (wave >> 1) * 64, wn = (wave & 1) * 64;

    int lr = lane >> 3;
    int lcol = ((lane & 7) ^ lr) << 3;
    const ushort_t* aBase = A + (size_t)(m0 + wave * 32 + lr) * K + lcol;
    const ushort_t* bBase = Bsrc + (size_t)(wave * 32 + lr) * K + lcol;

    f32x4 acc[4][4];
#pragma unroll
    for (int i = 0; i < 4; i++)
#pragma unroll
        for (int j = 0; j < 4; j++) acc[i][j] = (f32x4){0.f, 0.f, 0.f, 0.f};

    int nt = K >> 6;
    int swz = (l16 & 7) << 3;

    auto stage = [&](int buf, int kk) {
#pragma unroll
        for (int i = 0; i < 4; ++i) {
            gload16(aBase + (size_t)(i * 8) * K + kk,
                    &As[buf][(wave * 4 + i) * 512]);
            gload16(bBase + (size_t)(i * 8) * K + kk,
                    &Bs[buf][(wave * 4 + i) * 512]);
        }
    };

    stage(0, 0);
    __syncthreads();
    int cur = 0;
    for (int it = 0; it < nt; ++it) {
        if (it + 1 < nt) stage(cur ^ 1, (it + 1) * 64);
#pragma unroll
        for (int kstep = 0; kstep < 2; ++kstep) {
            int ko = kstep * 32 + quad * 8;
            int pc = ko ^ swz;
            short8 af[4], bfr[4];
#pragma unroll
            for (int i = 0; i < 4; i++)
                af[i] = *(const short8*)&As[cur][(wm + i * 16 + l16) * 64 + pc];
#pragma unroll
            for (int j = 0; j < 4; j++)
                bfr[j] = *(const short8*)&Bs[cur][(wn + j * 16 + l16) * 64 + pc];
#pragma unroll
            for (int i = 0; i < 4; i++)
#pragma unroll
                for (int j = 0; j < 4; j++)
                    acc[i][j] = __builtin_amdgcn_mfma_f32_16x16x32_bf16(
                        af[i], bfr[j], acc[i][j], 0, 0, 0);
        }
        __syncthreads();
        cur ^= 1;
    }

#pragma unroll
    for (int i = 0; i < 4; i++)
#pragma unroll
        for (int j = 0; j < 4; j++) {
            int gcol = by * 128 + wn + j * 16 + l16;
#pragma unroll
            for (int rr = 0; rr < 4; ++rr) {
                int grow = m0 + wm + i * 16 + quad * 4 + rr;
                C[(size_t)grow * Nmain + gcol] = acc[i][j][rr];
            }
        }
}

// ---------------------------------------------------------------------------
// Device-scope grid barrier (monotonic counter). All NBLK blocks are
// co-resident: 64 KB LDS -> hard cap 2 blocks/CU, capacity 512 >= 272.
// Release-add publishes this XCD's writes; acquire-spin invalidates caches.
// ---------------------------------------------------------------------------
__device__ __forceinline__ void grid_bar(int* bar, int phase) {
    __syncthreads();
    if (threadIdx.x == 0) {
        __threadfence();
        __hip_atomic_fetch_add(bar, 1, __ATOMIC_RELEASE,
                               __HIP_MEMORY_SCOPE_AGENT);
        int target = NBLK * (phase + 1);
        while (__hip_atomic_load(bar, __ATOMIC_ACQUIRE,
                                 __HIP_MEMORY_SCOPE_AGENT) < target)
            __builtin_amdgcn_s_sleep(2);
    }
    __syncthreads();
}

// ---------------------------------------------------------------------------
// Persistent-kernel phases
// ---------------------------------------------------------------------------
__device__ __forceinline__ void elem_work(int t, float* __restrict__ i_,
                                          float* __restrict__ u,
                                          ushort_t* __restrict__ a,
                                          const float* __restrict__ rp,
                                          const float* __restrict__ fp,
                                          const float* __restrict__ bias,
                                          float* __restrict__ out,
                                          float* __restrict__ act) {
    const int NU = 256 * 4096, NU4 = NU / 4;
    const int NF = 256 * 256, NF4 = NF / 4;
    int gtid = blockIdx.x * 256 + threadIdx.x;
    for (int id4 = gtid; id4 < NU4 + NF4; id4 += NBLK * 256) {
        if (id4 < NU4) {
            if (t >= ITER_TIME) continue;  // final pass only reduces f
            int id = id4 * 4;
            int b = id >> 12, n = id & 4095;
            f32x4 un;
            if (t == 0) {
                f32x4 iv = *(f32x4*)&i_[id] + *(const f32x4*)&bias[n];
                *(f32x4*)&i_[id] = iv;  // subsequent steps read biased i_
                un = iv;                // u0 = 0, r0 = 0
            } else {
                f32x4 s = *(const f32x4*)&i_[id];
#pragma unroll
                for (int k = 0; k < KS; ++k)
                    s += *(const f32x4*)&rp[(size_t)k * NU + id];
                un = DECAY * *(f32x4*)&u[id] + s;
            }
            *(f32x4*)&u[id] = un;
            short4v av;
#pragma unroll
            for (int j = 0; j < 4; ++j) {
                float ar = un[j] > 0.f ? un[j] : 0.f;
                __hip_bfloat16 h = __float2bfloat16(ar);
                av[j] = *(short*)&h;
            }
            *(short4v*)&a[id] = av;
            __builtin_nontemporal_store(
                un, (f32x4*)&act[(size_t)b * (ITER_TIME * 4096) +
                                 (size_t)t * 4096 + n]);
        } else {
            if (t == 0) continue;  // no f produced yet
            int id2 = (id4 - NU4) * 4;
            int b = id2 >> 8, d = id2 & 255;
            f32x4 fv = {0.f, 0.f, 0.f, 0.f};
#pragma unroll
            for (int k = 0; k < KS; ++k)
                fv += *(const f32x4*)&fp[(size_t)k * NF + id2];
            __builtin_nontemporal_store(
                fv, (f32x4*)&out[(size_t)b * (ITER_TIME * 256) +
                                 (size_t)(t - 1) * 256 + d]);
        }
    }
}

// One 128x128xklen GEMM tile of a @ [W_r | W_f]; item id = blockIdx.x.
__device__ __forceinline__ void gemm_tile(int blk, const ushort_t* __restrict__ A,
                                          const ushort_t* __restrict__ WrT,
                                          const ushort_t* __restrict__ WfT,
                                          float* __restrict__ rp,
                                          float* __restrict__ fp,
                                          ushort_t* __restrict__ AsB,
                                          ushort_t* __restrict__ BsB) {
    const int K = 4096, klen = K / KS, Nmain = 4096, N2 = 256, M = 256;
    int rem = blk % 68, ks = blk / 68;
    int mt = rem & 1, by = rem >> 1;  // by in [0,34): 0..31 W_r, 32..33 W_f
    int m0 = mt * 128;
    bool isB2 = (by >= 32);
    const ushort_t* Bsrc = isB2 ? WfT + (size_t)((by - 32) * 128) * K
                                : WrT + (size_t)(by * 128) * K;

    int t = threadIdx.x;
    int wave = t >> 6, lane = t & 63;
    int quad = lane >> 4, l16 = lane & 15;
    int wm = (wave >> 1) * 64, wn = (wave & 1) * 64;

    int lr = lane >> 3;
    int lcol = ((lane & 7) ^ lr) << 3;
    const ushort_t* aBase = A + (size_t)(m0 + wave * 32 + lr) * K + lcol;
    const ushort_t* bBase = Bsrc + (size_t)(wave * 32 + lr) * K + lcol;

    f32x4 acc[4][4];
#pragma unroll
    for (int i = 0; i < 4; i++)
#pragma unroll
        for (int j = 0; j < 4; j++) acc[i][j] = (f32x4){0.f, 0.f, 0.f, 0.f};

    int k0 = ks * klen;
    const int nt = klen >> 6;  // 16
    int swz = (l16 & 7) << 3;

    auto stage = [&](int buf, int kk) {
#pragma unroll
        for (int i = 0; i < 4; ++i) {
            gload16(aBase + (size_t)(i * 8) * K + kk,
                    &AsB[buf * 8192 + (wave * 4 + i) * 512]);
            gload16(bBase + (size_t)(i * 8) * K + kk,
                    &BsB[buf * 8192 + (wave * 4 + i) * 512]);
        }
    };

    stage(0, k0);
    __syncthreads();
    int cur = 0;
    for (int it = 0; it < nt; ++it) {
        if (it + 1 < nt) stage(cur ^ 1, k0 + (it + 1) * 64);
#pragma unroll
        for (int kstep = 0; kstep < 2; ++kstep) {
            int ko = kstep * 32 + quad * 8;
            int pc = ko ^ swz;
            short8 af[4], bfr[4];
#pragma unroll
            for (int i = 0; i < 4; i++)
                af[i] = *(const short8*)&AsB[cur * 8192 +
                                             (wm + i * 16 + l16) * 64 + pc];
#pragma unroll
            for (int j = 0; j < 4; j++)
                bfr[j] = *(const short8*)&BsB[cur * 8192 +
                                              (wn + j * 16 + l16) * 64 + pc];
#pragma unroll
            for (int i = 0; i < 4; i++)
#pragma unroll
                for (int j = 0; j < 4; j++)
                    acc[i][j] = __builtin_amdgcn_mfma_f32_16x16x32_bf16(
                        af[i], bfr[j], acc[i][j], 0, 0, 0);
        }
        __syncthreads();
        cur ^= 1;
    }

    // Epilogue: C/D layout col = lane&15, row = quad*4 + reg
#pragma unroll
    for (int i = 0; i < 4; i++)
#pragma unroll
        for (int j = 0; j < 4; j++) {
            int gcol = by * 128 + wn + j * 16 + l16;
#pragma unroll
            for (int rr = 0; rr < 4; ++rr) {
                int grow = m0 + wm + i * 16 + quad * 4 + rr;
                float v = acc[i][j][rr];
                if (!isB2) {
                    rp[(size_t)ks * M * Nmain + (size_t)grow * Nmain + gcol] = v;
                } else {
                    int c2 = gcol - Nmain;
                    fp[(size_t)ks * M * N2 + (size_t)grow * N2 + c2] = v;
                }
            }
        }
}

// ---------------------------------------------------------------------------
// Persistent kernel: the whole 32-step recurrence in one launch.
// Per step: elem phase (grid-stride, exactly 4 f32x4 items/thread) ->
// grid barrier -> GEMM phase (one 128x128xklen item/block) -> grid barrier.
// ---------------------------------------------------------------------------
__global__ __launch_bounds__(256, 2)
void persist(ushort_t* __restrict__ a, const ushort_t* __restrict__ WrT,
             const ushort_t* __restrict__ WfT, float* __restrict__ i_,
             float* __restrict__ u, float* __restrict__ rp,
             float* __restrict__ fp, const float* __restrict__ bias,
             float* __restrict__ out, float* __restrict__ act,
             int* __restrict__ bar) {
    __shared__ __attribute__((aligned(16))) ushort_t As[2 * 8192];
    __shared__ __attribute__((aligned(16))) ushort_t Bs[2 * 8192];
    int blk = blockIdx.x;
    int phase = 0;
    for (int t = 0; t < ITER_TIME; ++t) {
        elem_work(t, i_, u, a, rp, fp, bias, out, act);
        grid_bar(bar, phase++);
        gemm_tile(blk, a, WrT, WfT, rp, fp, As, Bs);
        grid_bar(bar, phase++);
    }
    elem_work(ITER_TIME, i_, u, a, rp, fp, bias, out, act);
}

// ---------------------------------------------------------------------------
// Workspace layout (KS = 4, peak ~62 MiB):
//   i_   0x0000000   4 MB  f32 [256][4096]
//   u    0x0400000   4 MB  f32 [256][4096]
//   a    0x0800000   2 MB  bf16 [256][4096]
//   rp   0x0A00000  16 MB  f32 [4][256][4096]   (WiT transiently lives here)
//   fp   0x1A00000   1 MB  f32 [4][256][256]
//   WrT  0x1B00000  32 MB  bf16 [4096][4096]
//   WfT  0x3B00000   2 MB  bf16 [256][4096]
//   xb   0x3D00000  .5 MB  bf16 [256][1024]
//   bar  0x3D80000   4 B   int (grid barrier counter)
// ---------------------------------------------------------------------------
extern "C" void kernel_launch(void* const* d_in, const int* in_sizes, int n_in,
                              void* d_out, int out_size, void* d_ws,
                              size_t ws_size, hipStream_t stream) {
    const float* x = (const float*)d_in[0];    // [256][1024] f32
    const float* Wi = (const float*)d_in[1];   // [1024][4096] f32
    const float* bb = (const float*)d_in[2];   // [4096] f32
    const float* Wr = (const float*)d_in[3];   // [4096][4096] f32
    const float* Wf = (const float*)d_in[4];   // [4096][256] f32

    float* out = (float*)d_out;                        // [256][32][256]
    float* act = out + (size_t)256 * ITER_TIME * 256;  // [256][32][4096]

    char* ws = (char*)d_ws;
    float* i_ = (float*)(ws + 0x0);
    float* u = (float*)(ws + 0x400000);
    __hip_bfloat16* a = (__hip_bfloat16*)(ws + 0x800000);
    float* rp = (float*)(ws + 0xA00000);
    float* fp = (float*)(ws + 0x1A00000);
    __hip_bfloat16* WrT = (__hip_bfloat16*)(ws + 0x1B00000);
    __hip_bfloat16* WfT = (__hip_bfloat16*)(ws + 0x3B00000);
    __hip_bfloat16* xb = (__hip_bfloat16*)(ws + 0x3D00000);
    int* bar = (int*)(ws + 0x3D80000);
    __hip_bfloat16* WiT = (__hip_bfloat16*)(ws + 0xA00000);  // transient in rp

    conv_f32_bf16<<<1024, 256, 0, stream>>>(x, xb, 256 * 1024, bar);
    dim3 tb(32, 32);
    transpose_f32_bf16<<<dim3(128, 32), tb, 0, stream>>>(Wi, WiT, 1024, 4096);
    transpose_f32_bf16<<<dim3(128, 128), tb, 0, stream>>>(Wr, WrT, 4096, 4096);
    transpose_f32_bf16<<<dim3(8, 128), tb, 0, stream>>>(Wf, WfT, 4096, 256);

    // i_ = x @ W_i
    gemm_wi<<<dim3(2, 32), 256, 0, stream>>>((const ushort_t*)xb,
                                             (const ushort_t*)WiT, i_, 1024,
                                             4096);

    // Entire recurrence in one persistent launch.
    persist<<<NBLK, 256, 0, stream>>>(
        (ushort_t*)a, (const ushort_t*)WrT, (const ushort_t*)WfT, i_, u, rp,
        fp, bb, out, act, bar);
}